// Round 8
// baseline (222.741 us; speedup 1.0000x reference)
//
#include <hip/hip_runtime.h>
#include <math.h>

#define NROWS  500000
#define NCHK   7813      // ceil(500000/64)
#define EPSV   1e-5f

typedef __bf16 bf16_t;
typedef __bf16 bf16x4 __attribute__((ext_vector_type(4)));
typedef __bf16 bf16x8 __attribute__((ext_vector_type(8)));
typedef float  f32x4  __attribute__((ext_vector_type(4)));

// ---- ws layout (byte offsets) ----
static const size_t GT_OFF   = 131072;   // gramTot 16384 f32 (64KB)
static const size_t WB_OFF   = 327680;   // W bf16 (32KB)
static const size_t MEAN_OFF = 360448;   // 128 f32
static const size_t BIAS_OFF = 360960;   // 128 f32
static const size_t CS_OFF   = 393216;   // colsum partials G*128 f32
static const size_t GRAM_OFF = 1048576;  // gram partials G*16384 f32

// ============ Kernel 1: column sums + Gram partials (bf16 MFMA) =============
// UNCHANGED from round 6/7 (verified). Feature-major XOR-swizzled LDS staging:
// element (f, s) at  f*64 + (((s>>3) ^ kf(f))<<3) + (s&7),  kf(f)=(f^(f>>3))&7.
__global__ __launch_bounds__(256) void k_stats(const float* __restrict__ X,
        float* __restrict__ csPart, float* __restrict__ gramPart) {
    __shared__ bf16_t sxtT[2][8192];    // [buf][f-major 128x64 swizzled] 32KB
    __shared__ float  scs[256][4];
    const int t    = threadIdx.x;
    const int lane = t & 63;
    const int w    = t >> 6;     // wave 0..3
    const int oct  = t >> 5;     // sample octet 0..7
    const int fg4  = t & 31;     // feature quad 0..31
    const int cl   = lane & 15;
    const int kq   = lane >> 4;
    const int G    = gridDim.x;

    f32x4 acc[2][8];
    #pragma unroll
    for (int a = 0; a < 2; a++)
        #pragma unroll
        for (int b = 0; b < 8; b++)
            acc[a][b] = (f32x4){0.f, 0.f, 0.f, 0.f};
    float cs0 = 0.f, cs1 = 0.f, cs2 = 0.f, cs3 = 0.f;

    f32x4 R[8];

    auto KF = [](int f) { return (f ^ (f >> 3)) & 7; };

    auto GLOADC = [&](int ch) {
        const size_t row0 = (size_t)ch << 6;
        #pragma unroll
        for (int i = 0; i < 8; i++) {
            const size_t row = row0 + oct * 8 + i;
            R[i] = (row < NROWS)
                 ? *reinterpret_cast<const f32x4*>(X + row * 128 + fg4 * 4)
                 : (f32x4){0.f, 0.f, 0.f, 0.f};
        }
    };
    auto DSWRITEC = [&](int buf) {
        #pragma unroll
        for (int i = 0; i < 8; i++) {
            cs0 += R[i][0]; cs1 += R[i][1]; cs2 += R[i][2]; cs3 += R[i][3];
        }
        bf16_t* S = sxtT[buf];
        #pragma unroll
        for (int j = 0; j < 4; j++) {
            const int f = fg4 * 4 + j;
            const int g = oct ^ KF(f);
            bf16x8 v;
            #pragma unroll
            for (int i = 0; i < 8; i++) v[i] = (bf16_t)R[i][j];
            *reinterpret_cast<bf16x8*>(&S[f * 64 + g * 8]) = v;
        }
    };
    auto MFMAC = [&](int buf) {
        const bf16_t* S = sxtT[buf];
        #pragma unroll
        for (int kb = 0; kb < 2; kb++) {
            const int gq = kb * 4 + kq;            // sample-group index
            bf16x8 fa[2];
            #pragma unroll
            for (int a = 0; a < 2; a++) {
                const int f = (w * 2 + a) * 16 + cl;
                fa[a] = *reinterpret_cast<const bf16x8*>(&S[f * 64 + ((gq ^ KF(f)) << 3)]);
            }
            #pragma unroll
            for (int b = 0; b < 8; b++) {
                const int f = b * 16 + cl;
                const bf16x8 fb = *reinterpret_cast<const bf16x8*>(&S[f * 64 + ((gq ^ KF(f)) << 3)]);
                acc[0][b] = __builtin_amdgcn_mfma_f32_16x16x32_bf16(fa[0], fb, acc[0][b], 0, 0, 0);
                acc[1][b] = __builtin_amdgcn_mfma_f32_16x16x32_bf16(fa[1], fb, acc[1][b], 0, 0, 0);
            }
        }
    };

    int ch0 = blockIdx.x;
    GLOADC(ch0);
    DSWRITEC(0);
    __syncthreads();
    for (;;) {
        const int ch1 = ch0 + G;
        const bool v1 = ch1 < NCHK;
        if (v1) GLOADC(ch1);
        MFMAC(0);
        if (v1) DSWRITEC(1);
        __syncthreads();
        if (!v1) break;
        const int ch2 = ch1 + G;
        const bool v2 = ch2 < NCHK;
        if (v2) GLOADC(ch2);
        MFMAC(1);
        if (v2) DSWRITEC(0);
        __syncthreads();
        if (!v2) break;
        ch0 = ch2;
    }

    float* gp = gramPart + (size_t)blockIdx.x * 16384;
    #pragma unroll
    for (int a = 0; a < 2; a++)
        #pragma unroll
        for (int b = 0; b < 8; b++)
            #pragma unroll
            for (int r = 0; r < 4; r++) {
                const int row = (w * 2 + a) * 16 + kq * 4 + r;
                const int col = b * 16 + cl;
                gp[row * 128 + col] = acc[a][b][r];
            }
    scs[t][0] = cs0; scs[t][1] = cs1; scs[t][2] = cs2; scs[t][3] = cs3;
    __syncthreads();
    if (t < 128) {
        float s = 0.f;
        #pragma unroll
        for (int q = 0; q < 8; q++) s += scs[q * 32 + (t >> 2)][t & 3];
        csPart[(size_t)blockIdx.x * 128 + t] = s;
    }
}

// ============ Kernel 2: full coalesced reduction -> gramTot + mean ==========
// Blocks 0..255: block b produces final gramTot[b*64 .. b*64+63]. 256 threads
// = 4 wave-slices over g (stride 4), each wave reads 256B contiguous per g,
// 8-deep unrolled (2MB in flight grid-wide), LDS 4-way fold. Block 256: mean.
__global__ __launch_bounds__(256) void k_gred(const float* __restrict__ gramPart,
        const float* __restrict__ csPart, float* __restrict__ gramTot,
        float* __restrict__ mean, int G) {
    const int t = threadIdx.x;
    const int b = blockIdx.x;
    if (b == 256) {                       // ---- mean ----
        if (t < 128) {
            float s = 0.f;
            int g = 0;
            for (; g + 8 <= G; g += 8) {
                float p[8];
                #pragma unroll
                for (int u = 0; u < 8; u++) p[u] = csPart[(size_t)(g + u) * 128 + t];
                s += ((p[0] + p[1]) + (p[2] + p[3])) + ((p[4] + p[5]) + (p[6] + p[7]));
            }
            for (; g < G; g++) s += csPart[(size_t)g * 128 + t];
            mean[t] = s * (1.0f / (float)NROWS);
        }
        return;
    }
    const int e  = b * 64 + (t & 63);
    const int sl = t >> 6;                // g-slice 0..3
    float s = 0.f;
    int g = sl;
    for (; g + 28 < G; g += 32) {         // 8 loads of stride-4 per iter
        float v[8];
        #pragma unroll
        for (int u = 0; u < 8; u++)
            v[u] = gramPart[(size_t)(g + 4 * u) * 16384 + e];
        s += ((v[0] + v[1]) + (v[2] + v[3])) + ((v[4] + v[5]) + (v[6] + v[7]));
    }
    for (; g < G; g += 4)
        s += gramPart[(size_t)g * 16384 + e];
    __shared__ float red[4][64];
    red[sl][t & 63] = s;
    __syncthreads();
    if (t < 64)
        gramTot[b * 64 + t] = (red[0][t] + red[1][t]) + (red[2][t] + red[3][t]);
}

// ============ Kernel 3: fused Sigma->Sn, Newton-Schulz x5, W, bias ==========
// As round 5 (verified): phase 0 reads the 64KB final gramTot only.
__global__ __launch_bounds__(512) void k_ns(const float* __restrict__ gramTot,
        const float* __restrict__ mean, const float* __restrict__ Rg,
        bf16_t* __restrict__ Wb, float* __restrict__ bias) {
    __shared__ bf16_t sPh[16384], sPl[16384], sSn[16384], sTT[16384];
    const int t = threadIdx.x;
    const int w = t >> 6, lane = t & 63;
    const int cl = lane & 15, kq = lane >> 4;

    float sig[32];
    float tr = 0.f;
    #pragma unroll
    for (int i = 0; i < 32; i++) {
        const int e = t + (i << 9);
        const int r = e >> 7, c = e & 127;
        float s = gramTot[e] * (1.0f / (float)NROWS) - mean[r] * mean[c];
        if (r == c) { s += EPSV; tr += s; }
        sig[i] = s;
    }
    float* rs = reinterpret_cast<float*>(sTT);
    rs[t] = tr;
    __syncthreads();
    #pragma unroll
    for (int off = 256; off > 0; off >>= 1) {
        if (t < off) rs[t] += rs[t + off];
        __syncthreads();
    }
    const float rTr = 1.0f / rs[0];
    __syncthreads();
    #pragma unroll
    for (int i = 0; i < 32; i++) {
        const int e = t + (i << 9);
        const int r = e >> 7, c = e & 127;
        const int ix = r * 128 + (c ^ ((r & 7) << 3));
        const float snv = sig[i] * rTr;
        sSn[ix] = (bf16_t)snv;
        const float p0 = ((r == c) ? 1.5f : 0.f) - 0.5f * snv;
        const bf16_t ph = (bf16_t)p0;
        sPh[ix] = ph;
        sPl[ix] = (bf16_t)(p0 - (float)ph);
    }
    __syncthreads();

    f32x4 acc[8];
    auto NSMM = [&](const bf16_t* __restrict__ Bm) {
        #pragma unroll
        for (int ct = 0; ct < 8; ct++) acc[ct] = (f32x4){0.f, 0.f, 0.f, 0.f};
        const int ra = w * 16 + cl;
        #pragma unroll
        for (int kb = 0; kb < 4; kb++) {
            const int k0 = kb * 32 + kq * 8;
            const int ia = ra * 128 + (k0 ^ ((ra & 7) << 3));
            const bf16x8 ah = *reinterpret_cast<const bf16x8*>(&sPh[ia]);
            const bf16x8 al = *reinterpret_cast<const bf16x8*>(&sPl[ia]);
            #pragma unroll
            for (int ct = 0; ct < 8; ct++) {
                const int rb = ct * 16 + cl;
                const bf16x8 bb = *reinterpret_cast<const bf16x8*>(
                    &Bm[rb * 128 + (k0 ^ ((rb & 7) << 3))]);
                acc[ct] = __builtin_amdgcn_mfma_f32_16x16x32_bf16(ah, bb, acc[ct], 0, 0, 0);
                acc[ct] = __builtin_amdgcn_mfma_f32_16x16x32_bf16(al, bb, acc[ct], 0, 0, 0);
            }
        }
    };
    auto WRT = [&](bf16_t* __restrict__ D) {
        #pragma unroll
        for (int ct = 0; ct < 8; ct++)
            #pragma unroll
            for (int r = 0; r < 4; r++) {
                const int ro = w * 16 + kq * 4 + r, co = ct * 16 + cl;
                D[ro * 128 + (co ^ ((ro & 7) << 3))] = (bf16_t)acc[ct][r];
            }
    };

    for (int it = 0; it < 4; it++) {
        NSMM(sSn);
        WRT(sTT);
        __syncthreads();
        NSMM(sTT);
        __syncthreads();
        WRT(sTT);
        __syncthreads();
        NSMM(sTT);
        #pragma unroll
        for (int ct = 0; ct < 8; ct++)
            #pragma unroll
            for (int r = 0; r < 4; r++) {
                const int ro = w * 16 + kq * 4 + r, co = ct * 16 + cl;
                const int ix = ro * 128 + (co ^ ((ro & 7) << 3));
                const float pold = (float)sPh[ix] + (float)sPl[ix];
                const float pn = 1.5f * pold - 0.5f * acc[ct][r];
                const bf16_t ph = (bf16_t)pn;
                sPh[ix] = ph;
                sPl[ix] = (bf16_t)(pn - (float)ph);
            }
        __syncthreads();
    }

    const float scal = sqrtf(rTr);
    #pragma unroll
    for (int ct = 0; ct < 8; ct++) acc[ct] = (f32x4){0.f, 0.f, 0.f, 0.f};
    const int ra = w * 16 + cl;
    #pragma unroll
    for (int kb = 0; kb < 4; kb++) {
        const int k0 = kb * 32 + kq * 8;
        const float4 rv0 = *reinterpret_cast<const float4*>(&Rg[ra * 128 + k0]);
        const float4 rv1 = *reinterpret_cast<const float4*>(&Rg[ra * 128 + k0 + 4]);
        const float rv[8] = {rv0.x, rv0.y, rv0.z, rv0.w, rv1.x, rv1.y, rv1.z, rv1.w};
        bf16x8 ah, al;
        #pragma unroll
        for (int j = 0; j < 8; j++) {
            ah[j] = (bf16_t)rv[j];
            al[j] = (bf16_t)(rv[j] - (float)ah[j]);
        }
        #pragma unroll
        for (int ct = 0; ct < 8; ct++) {
            const int rb = ct * 16 + cl;
            const int ib = rb * 128 + (k0 ^ ((rb & 7) << 3));
            const bf16x8 bh = *reinterpret_cast<const bf16x8*>(&sPh[ib]);
            const bf16x8 bl = *reinterpret_cast<const bf16x8*>(&sPl[ib]);
            acc[ct] = __builtin_amdgcn_mfma_f32_16x16x32_bf16(ah, bh, acc[ct], 0, 0, 0);
            acc[ct] = __builtin_amdgcn_mfma_f32_16x16x32_bf16(al, bh, acc[ct], 0, 0, 0);
            acc[ct] = __builtin_amdgcn_mfma_f32_16x16x32_bf16(ah, bl, acc[ct], 0, 0, 0);
        }
    }
    float pb[4] = {0.f, 0.f, 0.f, 0.f};
    #pragma unroll
    for (int ct = 0; ct < 8; ct++) {
        const float mv = mean[ct * 16 + cl];
        #pragma unroll
        for (int r = 0; r < 4; r++) {
            const float wv = acc[ct][r] * scal;
            Wb[(w * 16 + kq * 4 + r) * 128 + ct * 16 + cl] = (bf16_t)wv;
            pb[r] += wv * mv;
        }
    }
    #pragma unroll
    for (int r = 0; r < 4; r++) {
        float v = pb[r];
        v += __shfl_xor(v, 1);
        v += __shfl_xor(v, 2);
        v += __shfl_xor(v, 4);
        v += __shfl_xor(v, 8);
        if (cl == 0) bias[w * 16 + kq * 4 + r] = v;
    }
}

// ============ Kernel 4: out = X * W^T - bias (bf16 MFMA, split-X) ===========
// One 64-row tile per block (grid = NCHK): lower VGPR, 4 blocks/CU, X-loads
// issued before the staging barrier. Compute math identical to round 4.
__global__ __launch_bounds__(256) void k_out(const float* __restrict__ X,
        const bf16_t* __restrict__ Wb, const float* __restrict__ bias,
        float* __restrict__ out) {
    __shared__ bf16_t sW[128][136];
    __shared__ float sBias[128];
    const int t = threadIdx.x;
    const int w = t >> 6, lane = t & 63;
    const int cl = lane & 15, kq = lane >> 4;
    const size_t rowbase = (size_t)blockIdx.x * 64 + (size_t)w * 16;
    const bool valid = rowbase < NROWS;    // wave-uniform (NROWS%16==0)

    // X loads first: longest latency, overlaps W staging below.
    float4 B[8];
    {
        const float* xr = X + (rowbase + cl) * 128;
        #pragma unroll
        for (int kb = 0; kb < 4; kb++) {
            B[2*kb]   = valid ? *reinterpret_cast<const float4*>(xr + kb*32 + kq*8)
                              : float4{0.f,0.f,0.f,0.f};
            B[2*kb+1] = valid ? *reinterpret_cast<const float4*>(xr + kb*32 + kq*8 + 4)
                              : float4{0.f,0.f,0.f,0.f};
        }
    }
    #pragma unroll
    for (int i = 0; i < 16; i++) {
        const int idx = (t + (i << 8)) << 2;
        *reinterpret_cast<bf16x4*>(&sW[idx >> 7][idx & 127]) =
            *reinterpret_cast<const bf16x4*>(&Wb[idx]);
    }
    if (t < 128) sBias[t] = bias[t];
    __syncthreads();
    if (!valid) return;

    bf16x8 ah[4], al[4];
    #pragma unroll
    for (int kb = 0; kb < 4; kb++) {
        const float4 v0 = B[2*kb], v1 = B[2*kb+1];
        const float xv[8] = {v0.x, v0.y, v0.z, v0.w, v1.x, v1.y, v1.z, v1.w};
        bf16x8 h, l;
        #pragma unroll
        for (int j = 0; j < 8; j++) {
            h[j] = (bf16_t)xv[j];
            l[j] = (bf16_t)(xv[j] - (float)h[j]);
        }
        ah[kb] = h; al[kb] = l;
    }
    #pragma unroll
    for (int ct = 0; ct < 8; ct++) {
        f32x4 acc = (f32x4){0.f, 0.f, 0.f, 0.f};
        const int d = ct * 16 + cl;
        #pragma unroll
        for (int kb = 0; kb < 4; kb++) {
            const bf16x8 bf = *reinterpret_cast<const bf16x8*>(&sW[d][kb*32 + kq*8]);
            acc = __builtin_amdgcn_mfma_f32_16x16x32_bf16(al[kb], bf, acc, 0, 0, 0);
            acc = __builtin_amdgcn_mfma_f32_16x16x32_bf16(ah[kb], bf, acc, 0, 0, 0);
        }
        const float bc = sBias[d];
        #pragma unroll
        for (int r = 0; r < 4; r++)
            out[(rowbase + kq*4 + r) * 128 + d] = acc[r] - bc;
    }
}

extern "C" void kernel_launch(void* const* d_in, const int* in_sizes, int n_in,
                              void* d_out, int out_size, void* d_ws, size_t ws_size,
                              hipStream_t stream) {
    const float* X = (const float*)d_in[0];
    const float* R = (const float*)d_in[1];   // running_rot[0], row-major [d][c]
    float* out = (float*)d_out;
    char* ws = (char*)d_ws;
    float*  gramTot = (float*)(ws + GT_OFF);
    bf16_t* Wb      = (bf16_t*)(ws + WB_OFF);
    float*  mean    = (float*)(ws + MEAN_OFF);
    float*  bias    = (float*)(ws + BIAS_OFF);
    float*  csPart  = (float*)(ws + CS_OFF);

    int G = 512;
    size_t avail = (ws_size > GRAM_OFF) ? (ws_size - GRAM_OFF) : 0;
    if (avail < (size_t)G * 65536) {
        G = (int)(avail / 65536);
        if (G < 1) G = 1;
        if (G > 512) G = 512;
    }
    float* gramPart = (float*)(ws + GRAM_OFF);

    k_stats<<<dim3(G), dim3(256), 0, stream>>>(X, csPart, gramPart);
    k_gred<<<dim3(257), dim3(256), 0, stream>>>(gramPart, csPart, gramTot, mean, G);
    k_ns<<<dim3(1), dim3(512), 0, stream>>>(gramTot, mean, R, Wb, bias);
    k_out<<<dim3(NCHK), dim3(256), 0, stream>>>(X, Wb, bias, out);
}

// Round 9
// 219.451 us; speedup vs baseline: 1.0150x; 1.0150x over previous
//
#include <hip/hip_runtime.h>
#include <math.h>

#define NROWS  500000
#define NCHK   7813      // ceil(500000/64)
#define EPSV   1e-5f

typedef __bf16 bf16_t;
typedef __bf16 bf16x4 __attribute__((ext_vector_type(4)));
typedef __bf16 bf16x8 __attribute__((ext_vector_type(8)));
typedef float  f32x4  __attribute__((ext_vector_type(4)));

// ---- ws layout (byte offsets) ----
static const size_t GT_OFF   = 131072;   // gramTot 16384 f32 (64KB)
static const size_t WB_OFF   = 327680;   // W bf16 (32KB)
static const size_t MEAN_OFF = 360448;   // 128 f32
static const size_t BIAS_OFF = 360960;   // 128 f32
static const size_t CS_OFF   = 393216;   // colsum partials G*128 f32
static const size_t GRAM_OFF = 1048576;  // gram partials G*16384 f32

// ============ Kernel 1: column sums + Gram partials (bf16 MFMA) =============
// UNCHANGED from round 6/7/8 (verified). Feature-major XOR-swizzled staging.
__global__ __launch_bounds__(256) void k_stats(const float* __restrict__ X,
        float* __restrict__ csPart, float* __restrict__ gramPart) {
    __shared__ bf16_t sxtT[2][8192];    // [buf][f-major 128x64 swizzled] 32KB
    __shared__ float  scs[256][4];
    const int t    = threadIdx.x;
    const int lane = t & 63;
    const int w    = t >> 6;     // wave 0..3
    const int oct  = t >> 5;     // sample octet 0..7
    const int fg4  = t & 31;     // feature quad 0..31
    const int cl   = lane & 15;
    const int kq   = lane >> 4;
    const int G    = gridDim.x;

    f32x4 acc[2][8];
    #pragma unroll
    for (int a = 0; a < 2; a++)
        #pragma unroll
        for (int b = 0; b < 8; b++)
            acc[a][b] = (f32x4){0.f, 0.f, 0.f, 0.f};
    float cs0 = 0.f, cs1 = 0.f, cs2 = 0.f, cs3 = 0.f;

    f32x4 R[8];

    auto KF = [](int f) { return (f ^ (f >> 3)) & 7; };

    auto GLOADC = [&](int ch) {
        const size_t row0 = (size_t)ch << 6;
        #pragma unroll
        for (int i = 0; i < 8; i++) {
            const size_t row = row0 + oct * 8 + i;
            R[i] = (row < NROWS)
                 ? *reinterpret_cast<const f32x4*>(X + row * 128 + fg4 * 4)
                 : (f32x4){0.f, 0.f, 0.f, 0.f};
        }
    };
    auto DSWRITEC = [&](int buf) {
        #pragma unroll
        for (int i = 0; i < 8; i++) {
            cs0 += R[i][0]; cs1 += R[i][1]; cs2 += R[i][2]; cs3 += R[i][3];
        }
        bf16_t* S = sxtT[buf];
        #pragma unroll
        for (int j = 0; j < 4; j++) {
            const int f = fg4 * 4 + j;
            const int g = oct ^ KF(f);
            bf16x8 v;
            #pragma unroll
            for (int i = 0; i < 8; i++) v[i] = (bf16_t)R[i][j];
            *reinterpret_cast<bf16x8*>(&S[f * 64 + g * 8]) = v;
        }
    };
    auto MFMAC = [&](int buf) {
        const bf16_t* S = sxtT[buf];
        #pragma unroll
        for (int kb = 0; kb < 2; kb++) {
            const int gq = kb * 4 + kq;            // sample-group index
            bf16x8 fa[2];
            #pragma unroll
            for (int a = 0; a < 2; a++) {
                const int f = (w * 2 + a) * 16 + cl;
                fa[a] = *reinterpret_cast<const bf16x8*>(&S[f * 64 + ((gq ^ KF(f)) << 3)]);
            }
            #pragma unroll
            for (int b = 0; b < 8; b++) {
                const int f = b * 16 + cl;
                const bf16x8 fb = *reinterpret_cast<const bf16x8*>(&S[f * 64 + ((gq ^ KF(f)) << 3)]);
                acc[0][b] = __builtin_amdgcn_mfma_f32_16x16x32_bf16(fa[0], fb, acc[0][b], 0, 0, 0);
                acc[1][b] = __builtin_amdgcn_mfma_f32_16x16x32_bf16(fa[1], fb, acc[1][b], 0, 0, 0);
            }
        }
    };

    int ch0 = blockIdx.x;
    GLOADC(ch0);
    DSWRITEC(0);
    __syncthreads();
    for (;;) {
        const int ch1 = ch0 + G;
        const bool v1 = ch1 < NCHK;
        if (v1) GLOADC(ch1);
        MFMAC(0);
        if (v1) DSWRITEC(1);
        __syncthreads();
        if (!v1) break;
        const int ch2 = ch1 + G;
        const bool v2 = ch2 < NCHK;
        if (v2) GLOADC(ch2);
        MFMAC(1);
        if (v2) DSWRITEC(0);
        __syncthreads();
        if (!v2) break;
        ch0 = ch2;
    }

    float* gp = gramPart + (size_t)blockIdx.x * 16384;
    #pragma unroll
    for (int a = 0; a < 2; a++)
        #pragma unroll
        for (int b = 0; b < 8; b++)
            #pragma unroll
            for (int r = 0; r < 4; r++) {
                const int row = (w * 2 + a) * 16 + kq * 4 + r;
                const int col = b * 16 + cl;
                gp[row * 128 + col] = acc[a][b][r];
            }
    scs[t][0] = cs0; scs[t][1] = cs1; scs[t][2] = cs2; scs[t][3] = cs3;
    __syncthreads();
    if (t < 128) {
        float s = 0.f;
        #pragma unroll
        for (int q = 0; q < 8; q++) s += scs[q * 32 + (t >> 2)][t & 3];
        csPart[(size_t)blockIdx.x * 128 + t] = s;
    }
}

// ============ Kernel 2: full coalesced reduction -> gramTot + mean ==========
// UNCHANGED from round 8 (verified).
__global__ __launch_bounds__(256) void k_gred(const float* __restrict__ gramPart,
        const float* __restrict__ csPart, float* __restrict__ gramTot,
        float* __restrict__ mean, int G) {
    const int t = threadIdx.x;
    const int b = blockIdx.x;
    if (b == 256) {                       // ---- mean ----
        if (t < 128) {
            float s = 0.f;
            int g = 0;
            for (; g + 8 <= G; g += 8) {
                float p[8];
                #pragma unroll
                for (int u = 0; u < 8; u++) p[u] = csPart[(size_t)(g + u) * 128 + t];
                s += ((p[0] + p[1]) + (p[2] + p[3])) + ((p[4] + p[5]) + (p[6] + p[7]));
            }
            for (; g < G; g++) s += csPart[(size_t)g * 128 + t];
            mean[t] = s * (1.0f / (float)NROWS);
        }
        return;
    }
    const int e  = b * 64 + (t & 63);
    const int sl = t >> 6;                // g-slice 0..3
    float s = 0.f;
    int g = sl;
    for (; g + 28 < G; g += 32) {         // 8 loads of stride-4 per iter
        float v[8];
        #pragma unroll
        for (int u = 0; u < 8; u++)
            v[u] = gramPart[(size_t)(g + 4 * u) * 16384 + e];
        s += ((v[0] + v[1]) + (v[2] + v[3])) + ((v[4] + v[5]) + (v[6] + v[7]));
    }
    for (; g < G; g += 4)
        s += gramPart[(size_t)g * 16384 + e];
    __shared__ float red[4][64];
    red[sl][t & 63] = s;
    __syncthreads();
    if (t < 64)
        gramTot[b * 64 + t] = (red[0][t] + red[1][t]) + (red[2][t] + red[3][t]);
}

// ============ Kernel 3: fused Sigma->Sn, Newton-Schulz x5, W, bias ==========
// 4-wave restructure: wave w owns TWO 16-row bands (rows 32w..32w+31) -> B-frag
// LDS traffic halves (320->192 KB/NSMM). WRT / P-update use ds_write_b64 via
// TRANSPOSED positions (every NS matrix is symmetric: P=poly(Sn) commutes).
__global__ __launch_bounds__(256) void k_ns(const float* __restrict__ gramTot,
        const float* __restrict__ mean, const float* __restrict__ Rg,
        bf16_t* __restrict__ Wb, float* __restrict__ bias) {
    __shared__ bf16_t sPh[16384], sPl[16384], sSn[16384], sTT[16384];
    const int t = threadIdx.x;
    const int w = t >> 6, lane = t & 63;
    const int cl = lane & 15, kq = lane >> 4;

    // ---- phase 0a: trace from the diagonal only ----
    float* rs = reinterpret_cast<float*>(sTT);
    float dv = 0.f;
    if (t < 128) {
        const float m = mean[t];
        dv = gramTot[t * 129] * (1.0f / (float)NROWS) - m * m + EPSV;
    }
    rs[t] = dv;
    __syncthreads();
    #pragma unroll
    for (int off = 128; off > 0; off >>= 1) {
        if (t < off) rs[t] += rs[t + off];
        __syncthreads();
    }
    const float rTr = 1.0f / rs[0];
    __syncthreads();
    // ---- phase 0b: Sn (bf16), P0 = 1.5I - 0.5*Sn (split hi/lo) ----
    for (int i = 0; i < 64; i++) {
        const int e = t + (i << 8);
        const int r = e >> 7, c = e & 127;
        float s = gramTot[e] * (1.0f / (float)NROWS) - mean[r] * mean[c];
        if (r == c) s += EPSV;
        const int ix = r * 128 + (c ^ ((r & 7) << 3));
        const float snv = s * rTr;
        sSn[ix] = (bf16_t)snv;
        const float p0 = ((r == c) ? 1.5f : 0.f) - 0.5f * snv;
        const bf16_t ph = (bf16_t)p0;
        sPh[ix] = ph;
        sPl[ix] = (bf16_t)(p0 - (float)ph);
    }
    __syncthreads();

    f32x4 acc[2][8];
    auto NSMM = [&](const bf16_t* __restrict__ Bm) {
        #pragma unroll
        for (int a = 0; a < 2; a++)
            #pragma unroll
            for (int ct = 0; ct < 8; ct++) acc[a][ct] = (f32x4){0.f, 0.f, 0.f, 0.f};
        #pragma unroll
        for (int kb = 0; kb < 4; kb++) {
            const int k0 = kb * 32 + kq * 8;
            bf16x8 ah[2], al[2];
            #pragma unroll
            for (int a = 0; a < 2; a++) {
                const int ra = w * 32 + a * 16 + cl;
                const int ia = ra * 128 + (k0 ^ ((ra & 7) << 3));
                ah[a] = *reinterpret_cast<const bf16x8*>(&sPh[ia]);
                al[a] = *reinterpret_cast<const bf16x8*>(&sPl[ia]);
            }
            #pragma unroll
            for (int ct = 0; ct < 8; ct++) {
                const int rb = ct * 16 + cl;
                const bf16x8 bb = *reinterpret_cast<const bf16x8*>(
                    &Bm[rb * 128 + (k0 ^ ((rb & 7) << 3))]);
                acc[0][ct] = __builtin_amdgcn_mfma_f32_16x16x32_bf16(ah[0], bb, acc[0][ct], 0, 0, 0);
                acc[0][ct] = __builtin_amdgcn_mfma_f32_16x16x32_bf16(al[0], bb, acc[0][ct], 0, 0, 0);
                acc[1][ct] = __builtin_amdgcn_mfma_f32_16x16x32_bf16(ah[1], bb, acc[1][ct], 0, 0, 0);
                acc[1][ct] = __builtin_amdgcn_mfma_f32_16x16x32_bf16(al[1], bb, acc[1][ct], 0, 0, 0);
            }
        }
    };
    // Transposed b64 write: acc (ro,co) stored at [co][ro0..ro0+3] (D == D^T).
    auto WRT = [&](bf16_t* __restrict__ D) {
        #pragma unroll
        for (int a = 0; a < 2; a++) {
            const int ro0 = w * 32 + a * 16 + kq * 4;
            #pragma unroll
            for (int ct = 0; ct < 8; ct++) {
                const int co = ct * 16 + cl;
                bf16x4 v = { (bf16_t)acc[a][ct][0], (bf16_t)acc[a][ct][1],
                             (bf16_t)acc[a][ct][2], (bf16_t)acc[a][ct][3] };
                *reinterpret_cast<bf16x4*>(&D[co * 128 + (ro0 ^ ((co & 7) << 3))]) = v;
            }
        }
    };

    for (int it = 0; it < 4; it++) {
        NSMM(sSn);               // T = P*Sn
        WRT(sTT);
        __syncthreads();
        NSMM(sTT);               // U = P*T
        __syncthreads();
        WRT(sTT);                // TT <- U
        __syncthreads();
        NSMM(sTT);               // D = P*U
        // P <- 1.5P - 0.5D, transposed b64 read-modify-write (slices disjoint)
        #pragma unroll
        for (int a = 0; a < 2; a++) {
            const int ro0 = w * 32 + a * 16 + kq * 4;
            #pragma unroll
            for (int ct = 0; ct < 8; ct++) {
                const int co = ct * 16 + cl;
                const int ix = co * 128 + (ro0 ^ ((co & 7) << 3));
                bf16x4 ph4 = *reinterpret_cast<const bf16x4*>(&sPh[ix]);
                bf16x4 pl4 = *reinterpret_cast<const bf16x4*>(&sPl[ix]);
                bf16x4 nh, nl;
                #pragma unroll
                for (int r = 0; r < 4; r++) {
                    const float pold = (float)ph4[r] + (float)pl4[r];
                    const float pn = 1.5f * pold - 0.5f * acc[a][ct][r];
                    nh[r] = (bf16_t)pn;
                    nl[r] = (bf16_t)(pn - (float)nh[r]);
                }
                *reinterpret_cast<bf16x4*>(&sPh[ix]) = nh;
                *reinterpret_cast<bf16x4*>(&sPl[ix]) = nl;
            }
        }
        __syncthreads();
    }

    // ---- W = R * P * sqrt(rTr); Wb (bf16) + bias = W*mean ----
    const float scal = sqrtf(rTr);
    #pragma unroll
    for (int a = 0; a < 2; a++)
        #pragma unroll
        for (int ct = 0; ct < 8; ct++) acc[a][ct] = (f32x4){0.f, 0.f, 0.f, 0.f};
    #pragma unroll
    for (int kb = 0; kb < 4; kb++) {
        const int k0 = kb * 32 + kq * 8;
        bf16x8 ah[2], al[2];
        #pragma unroll
        for (int a = 0; a < 2; a++) {
            const int ra = w * 32 + a * 16 + cl;
            const float4 rv0 = *reinterpret_cast<const float4*>(&Rg[ra * 128 + k0]);
            const float4 rv1 = *reinterpret_cast<const float4*>(&Rg[ra * 128 + k0 + 4]);
            const float rv[8] = {rv0.x, rv0.y, rv0.z, rv0.w, rv1.x, rv1.y, rv1.z, rv1.w};
            bf16x8 h, l;
            #pragma unroll
            for (int j = 0; j < 8; j++) {
                h[j] = (bf16_t)rv[j];
                l[j] = (bf16_t)(rv[j] - (float)h[j]);
            }
            ah[a] = h; al[a] = l;
        }
        #pragma unroll
        for (int ct = 0; ct < 8; ct++) {
            const int rb = ct * 16 + cl;
            const int ib = rb * 128 + (k0 ^ ((rb & 7) << 3));
            const bf16x8 bh = *reinterpret_cast<const bf16x8*>(&sPh[ib]);
            const bf16x8 bl = *reinterpret_cast<const bf16x8*>(&sPl[ib]);
            #pragma unroll
            for (int a = 0; a < 2; a++) {
                acc[a][ct] = __builtin_amdgcn_mfma_f32_16x16x32_bf16(ah[a], bh, acc[a][ct], 0, 0, 0);
                acc[a][ct] = __builtin_amdgcn_mfma_f32_16x16x32_bf16(al[a], bh, acc[a][ct], 0, 0, 0);
                acc[a][ct] = __builtin_amdgcn_mfma_f32_16x16x32_bf16(ah[a], bl, acc[a][ct], 0, 0, 0);
            }
        }
    }
    #pragma unroll
    for (int a = 0; a < 2; a++) {
        float pb[4] = {0.f, 0.f, 0.f, 0.f};
        #pragma unroll
        for (int ct = 0; ct < 8; ct++) {
            const float mv = mean[ct * 16 + cl];
            #pragma unroll
            for (int r = 0; r < 4; r++) {
                const float wv = acc[a][ct][r] * scal;
                Wb[(w * 32 + a * 16 + kq * 4 + r) * 128 + ct * 16 + cl] = (bf16_t)wv;
                pb[r] += wv * mv;
            }
        }
        #pragma unroll
        for (int r = 0; r < 4; r++) {
            float v = pb[r];
            v += __shfl_xor(v, 1);
            v += __shfl_xor(v, 2);
            v += __shfl_xor(v, 4);
            v += __shfl_xor(v, 8);
            if (cl == 0) bias[w * 32 + a * 16 + kq * 4 + r] = v;
        }
    }
}

// ============ Kernel 4: out = X * W^T - bias (bf16 MFMA, split-X) ===========
// As round 8, but REVERSED tile order: k_stats's forward sweep leaves the tail
// of X resident in the 256MB Infinity Cache; reading back-to-front turns a
// large fraction of the 256MB X re-read into L3 hits.
__global__ __launch_bounds__(256) void k_out(const float* __restrict__ X,
        const bf16_t* __restrict__ Wb, const float* __restrict__ bias,
        float* __restrict__ out) {
    __shared__ bf16_t sW[128][136];
    __shared__ float sBias[128];
    const int t = threadIdx.x;
    const int w = t >> 6, lane = t & 63;
    const int cl = lane & 15, kq = lane >> 4;
    const int tile = NCHK - 1 - blockIdx.x;          // reverse order
    const size_t rowbase = (size_t)tile * 64 + (size_t)w * 16;
    const bool valid = rowbase < NROWS;    // wave-uniform (NROWS%16==0)

    float4 B[8];
    {
        const float* xr = X + (rowbase + cl) * 128;
        #pragma unroll
        for (int kb = 0; kb < 4; kb++) {
            B[2*kb]   = valid ? *reinterpret_cast<const float4*>(xr + kb*32 + kq*8)
                              : float4{0.f,0.f,0.f,0.f};
            B[2*kb+1] = valid ? *reinterpret_cast<const float4*>(xr + kb*32 + kq*8 + 4)
                              : float4{0.f,0.f,0.f,0.f};
        }
    }
    #pragma unroll
    for (int i = 0; i < 16; i++) {
        const int idx = (t + (i << 8)) << 2;
        *reinterpret_cast<bf16x4*>(&sW[idx >> 7][idx & 127]) =
            *reinterpret_cast<const bf16x4*>(&Wb[idx]);
    }
    if (t < 128) sBias[t] = bias[t];
    __syncthreads();
    if (!valid) return;

    bf16x8 ah[4], al[4];
    #pragma unroll
    for (int kb = 0; kb < 4; kb++) {
        const float4 v0 = B[2*kb], v1 = B[2*kb+1];
        const float xv[8] = {v0.x, v0.y, v0.z, v0.w, v1.x, v1.y, v1.z, v1.w};
        bf16x8 h, l;
        #pragma unroll
        for (int j = 0; j < 8; j++) {
            h[j] = (bf16_t)xv[j];
            l[j] = (bf16_t)(xv[j] - (float)h[j]);
        }
        ah[kb] = h; al[kb] = l;
    }
    #pragma unroll
    for (int ct = 0; ct < 8; ct++) {
        f32x4 acc = (f32x4){0.f, 0.f, 0.f, 0.f};
        const int d = ct * 16 + cl;
        #pragma unroll
        for (int kb = 0; kb < 4; kb++) {
            const bf16x8 bf = *reinterpret_cast<const bf16x8*>(&sW[d][kb*32 + kq*8]);
            acc = __builtin_amdgcn_mfma_f32_16x16x32_bf16(al[kb], bf, acc, 0, 0, 0);
            acc = __builtin_amdgcn_mfma_f32_16x16x32_bf16(ah[kb], bf, acc, 0, 0, 0);
        }
        const float bc = sBias[d];
        #pragma unroll
        for (int r = 0; r < 4; r++)
            out[(rowbase + kq*4 + r) * 128 + d] = acc[r] - bc;
    }
}

extern "C" void kernel_launch(void* const* d_in, const int* in_sizes, int n_in,
                              void* d_out, int out_size, void* d_ws, size_t ws_size,
                              hipStream_t stream) {
    const float* X = (const float*)d_in[0];
    const float* R = (const float*)d_in[1];   // running_rot[0], row-major [d][c]
    float* out = (float*)d_out;
    char* ws = (char*)d_ws;
    float*  gramTot = (float*)(ws + GT_OFF);
    bf16_t* Wb      = (bf16_t*)(ws + WB_OFF);
    float*  mean    = (float*)(ws + MEAN_OFF);
    float*  bias    = (float*)(ws + BIAS_OFF);
    float*  csPart  = (float*)(ws + CS_OFF);

    int G = 512;
    size_t avail = (ws_size > GRAM_OFF) ? (ws_size - GRAM_OFF) : 0;
    if (avail < (size_t)G * 65536) {
        G = (int)(avail / 65536);
        if (G < 1) G = 1;
        if (G > 512) G = 512;
    }
    float* gramPart = (float*)(ws + GRAM_OFF);

    k_stats<<<dim3(G), dim3(256), 0, stream>>>(X, csPart, gramPart);
    k_gred<<<dim3(257), dim3(256), 0, stream>>>(gramPart, csPart, gramTot, mean, G);
    k_ns<<<dim3(1), dim3(256), 0, stream>>>(gramTot, mean, R, Wb, bias);
    k_out<<<dim3(NCHK), dim3(256), 0, stream>>>(X, Wb, bias, out);
}

// Round 10
// 210.328 us; speedup vs baseline: 1.0590x; 1.0434x over previous
//
#include <hip/hip_runtime.h>
#include <math.h>

#define NROWS  500000
#define NCHK   7813      // ceil(500000/64)
#define EPSV   1e-5f

typedef __bf16 bf16_t;
typedef __bf16 bf16x4 __attribute__((ext_vector_type(4)));
typedef __bf16 bf16x8 __attribute__((ext_vector_type(8)));
typedef float  f32x4  __attribute__((ext_vector_type(4)));

// ---- ws layout (byte offsets) ----
static const size_t GT_OFF   = 131072;   // gramTot 16384 f32 (64KB)
static const size_t WB_OFF   = 327680;   // W bf16 (32KB)
static const size_t MEAN_OFF = 360448;   // 128 f32
static const size_t BIAS_OFF = 360960;   // 128 f32
static const size_t CS_OFF   = 393216;   // colsum partials G*128 f32
static const size_t GRAM_OFF = 1048576;  // gram partials G*16384 f32

// ============ Kernel 1: column sums + Gram partials (bf16 MFMA) =============
// UNCHANGED from rounds 6-9 (verified). Feature-major XOR-swizzled staging.
__global__ __launch_bounds__(256) void k_stats(const float* __restrict__ X,
        float* __restrict__ csPart, float* __restrict__ gramPart) {
    __shared__ bf16_t sxtT[2][8192];    // [buf][f-major 128x64 swizzled] 32KB
    __shared__ float  scs[256][4];
    const int t    = threadIdx.x;
    const int lane = t & 63;
    const int w    = t >> 6;     // wave 0..3
    const int oct  = t >> 5;     // sample octet 0..7
    const int fg4  = t & 31;     // feature quad 0..31
    const int cl   = lane & 15;
    const int kq   = lane >> 4;
    const int G    = gridDim.x;

    f32x4 acc[2][8];
    #pragma unroll
    for (int a = 0; a < 2; a++)
        #pragma unroll
        for (int b = 0; b < 8; b++)
            acc[a][b] = (f32x4){0.f, 0.f, 0.f, 0.f};
    float cs0 = 0.f, cs1 = 0.f, cs2 = 0.f, cs3 = 0.f;

    f32x4 R[8];

    auto KF = [](int f) { return (f ^ (f >> 3)) & 7; };

    auto GLOADC = [&](int ch) {
        const size_t row0 = (size_t)ch << 6;
        #pragma unroll
        for (int i = 0; i < 8; i++) {
            const size_t row = row0 + oct * 8 + i;
            R[i] = (row < NROWS)
                 ? *reinterpret_cast<const f32x4*>(X + row * 128 + fg4 * 4)
                 : (f32x4){0.f, 0.f, 0.f, 0.f};
        }
    };
    auto DSWRITEC = [&](int buf) {
        #pragma unroll
        for (int i = 0; i < 8; i++) {
            cs0 += R[i][0]; cs1 += R[i][1]; cs2 += R[i][2]; cs3 += R[i][3];
        }
        bf16_t* S = sxtT[buf];
        #pragma unroll
        for (int j = 0; j < 4; j++) {
            const int f = fg4 * 4 + j;
            const int g = oct ^ KF(f);
            bf16x8 v;
            #pragma unroll
            for (int i = 0; i < 8; i++) v[i] = (bf16_t)R[i][j];
            *reinterpret_cast<bf16x8*>(&S[f * 64 + g * 8]) = v;
        }
    };
    auto MFMAC = [&](int buf) {
        const bf16_t* S = sxtT[buf];
        #pragma unroll
        for (int kb = 0; kb < 2; kb++) {
            const int gq = kb * 4 + kq;            // sample-group index
            bf16x8 fa[2];
            #pragma unroll
            for (int a = 0; a < 2; a++) {
                const int f = (w * 2 + a) * 16 + cl;
                fa[a] = *reinterpret_cast<const bf16x8*>(&S[f * 64 + ((gq ^ KF(f)) << 3)]);
            }
            #pragma unroll
            for (int b = 0; b < 8; b++) {
                const int f = b * 16 + cl;
                const bf16x8 fb = *reinterpret_cast<const bf16x8*>(&S[f * 64 + ((gq ^ KF(f)) << 3)]);
                acc[0][b] = __builtin_amdgcn_mfma_f32_16x16x32_bf16(fa[0], fb, acc[0][b], 0, 0, 0);
                acc[1][b] = __builtin_amdgcn_mfma_f32_16x16x32_bf16(fa[1], fb, acc[1][b], 0, 0, 0);
            }
        }
    };

    int ch0 = blockIdx.x;
    GLOADC(ch0);
    DSWRITEC(0);
    __syncthreads();
    for (;;) {
        const int ch1 = ch0 + G;
        const bool v1 = ch1 < NCHK;
        if (v1) GLOADC(ch1);
        MFMAC(0);
        if (v1) DSWRITEC(1);
        __syncthreads();
        if (!v1) break;
        const int ch2 = ch1 + G;
        const bool v2 = ch2 < NCHK;
        if (v2) GLOADC(ch2);
        MFMAC(1);
        if (v2) DSWRITEC(0);
        __syncthreads();
        if (!v2) break;
        ch0 = ch2;
    }

    float* gp = gramPart + (size_t)blockIdx.x * 16384;
    #pragma unroll
    for (int a = 0; a < 2; a++)
        #pragma unroll
        for (int b = 0; b < 8; b++)
            #pragma unroll
            for (int r = 0; r < 4; r++) {
                const int row = (w * 2 + a) * 16 + kq * 4 + r;
                const int col = b * 16 + cl;
                gp[row * 128 + col] = acc[a][b][r];
            }
    scs[t][0] = cs0; scs[t][1] = cs1; scs[t][2] = cs2; scs[t][3] = cs3;
    __syncthreads();
    if (t < 128) {
        float s = 0.f;
        #pragma unroll
        for (int q = 0; q < 8; q++) s += scs[q * 32 + (t >> 2)][t & 3];
        csPart[(size_t)blockIdx.x * 128 + t] = s;
    }
}

// ============ Kernel 2: full coalesced reduction -> gramTot + mean ==========
// UNCHANGED from round 8/9 (verified).
__global__ __launch_bounds__(256) void k_gred(const float* __restrict__ gramPart,
        const float* __restrict__ csPart, float* __restrict__ gramTot,
        float* __restrict__ mean, int G) {
    const int t = threadIdx.x;
    const int b = blockIdx.x;
    if (b == 256) {                       // ---- mean ----
        if (t < 128) {
            float s = 0.f;
            int g = 0;
            for (; g + 8 <= G; g += 8) {
                float p[8];
                #pragma unroll
                for (int u = 0; u < 8; u++) p[u] = csPart[(size_t)(g + u) * 128 + t];
                s += ((p[0] + p[1]) + (p[2] + p[3])) + ((p[4] + p[5]) + (p[6] + p[7]));
            }
            for (; g < G; g++) s += csPart[(size_t)g * 128 + t];
            mean[t] = s * (1.0f / (float)NROWS);
        }
        return;
    }
    const int e  = b * 64 + (t & 63);
    const int sl = t >> 6;                // g-slice 0..3
    float s = 0.f;
    int g = sl;
    for (; g + 28 < G; g += 32) {         // 8 loads of stride-4 per iter
        float v[8];
        #pragma unroll
        for (int u = 0; u < 8; u++)
            v[u] = gramPart[(size_t)(g + 4 * u) * 16384 + e];
        s += ((v[0] + v[1]) + (v[2] + v[3])) + ((v[4] + v[5]) + (v[6] + v[7]));
    }
    for (; g < G; g += 4)
        s += gramPart[(size_t)g * 16384 + e];
    __shared__ float red[4][64];
    red[sl][t & 63] = s;
    __syncthreads();
    if (t < 64)
        gramTot[b * 64 + t] = (red[0][t] + red[1][t]) + (red[2][t] + red[3][t]);
}

// ============ Kernel 3: fused Sigma->Sn, Newton-Schulz x5, W, bias ==========
// UNCHANGED from round 9 (verified). 4 waves x 2 bands, symmetric-transpose
// b64 writes, split-bf16 P state.
__global__ __launch_bounds__(256) void k_ns(const float* __restrict__ gramTot,
        const float* __restrict__ mean, const float* __restrict__ Rg,
        bf16_t* __restrict__ Wb, float* __restrict__ bias) {
    __shared__ bf16_t sPh[16384], sPl[16384], sSn[16384], sTT[16384];
    const int t = threadIdx.x;
    const int w = t >> 6, lane = t & 63;
    const int cl = lane & 15, kq = lane >> 4;

    float* rs = reinterpret_cast<float*>(sTT);
    float dv = 0.f;
    if (t < 128) {
        const float m = mean[t];
        dv = gramTot[t * 129] * (1.0f / (float)NROWS) - m * m + EPSV;
    }
    rs[t] = dv;
    __syncthreads();
    #pragma unroll
    for (int off = 128; off > 0; off >>= 1) {
        if (t < off) rs[t] += rs[t + off];
        __syncthreads();
    }
    const float rTr = 1.0f / rs[0];
    __syncthreads();
    for (int i = 0; i < 64; i++) {
        const int e = t + (i << 8);
        const int r = e >> 7, c = e & 127;
        float s = gramTot[e] * (1.0f / (float)NROWS) - mean[r] * mean[c];
        if (r == c) s += EPSV;
        const int ix = r * 128 + (c ^ ((r & 7) << 3));
        const float snv = s * rTr;
        sSn[ix] = (bf16_t)snv;
        const float p0 = ((r == c) ? 1.5f : 0.f) - 0.5f * snv;
        const bf16_t ph = (bf16_t)p0;
        sPh[ix] = ph;
        sPl[ix] = (bf16_t)(p0 - (float)ph);
    }
    __syncthreads();

    f32x4 acc[2][8];
    auto NSMM = [&](const bf16_t* __restrict__ Bm) {
        #pragma unroll
        for (int a = 0; a < 2; a++)
            #pragma unroll
            for (int ct = 0; ct < 8; ct++) acc[a][ct] = (f32x4){0.f, 0.f, 0.f, 0.f};
        #pragma unroll
        for (int kb = 0; kb < 4; kb++) {
            const int k0 = kb * 32 + kq * 8;
            bf16x8 ah[2], al[2];
            #pragma unroll
            for (int a = 0; a < 2; a++) {
                const int ra = w * 32 + a * 16 + cl;
                const int ia = ra * 128 + (k0 ^ ((ra & 7) << 3));
                ah[a] = *reinterpret_cast<const bf16x8*>(&sPh[ia]);
                al[a] = *reinterpret_cast<const bf16x8*>(&sPl[ia]);
            }
            #pragma unroll
            for (int ct = 0; ct < 8; ct++) {
                const int rb = ct * 16 + cl;
                const bf16x8 bb = *reinterpret_cast<const bf16x8*>(
                    &Bm[rb * 128 + (k0 ^ ((rb & 7) << 3))]);
                acc[0][ct] = __builtin_amdgcn_mfma_f32_16x16x32_bf16(ah[0], bb, acc[0][ct], 0, 0, 0);
                acc[0][ct] = __builtin_amdgcn_mfma_f32_16x16x32_bf16(al[0], bb, acc[0][ct], 0, 0, 0);
                acc[1][ct] = __builtin_amdgcn_mfma_f32_16x16x32_bf16(ah[1], bb, acc[1][ct], 0, 0, 0);
                acc[1][ct] = __builtin_amdgcn_mfma_f32_16x16x32_bf16(al[1], bb, acc[1][ct], 0, 0, 0);
            }
        }
    };
    auto WRT = [&](bf16_t* __restrict__ D) {
        #pragma unroll
        for (int a = 0; a < 2; a++) {
            const int ro0 = w * 32 + a * 16 + kq * 4;
            #pragma unroll
            for (int ct = 0; ct < 8; ct++) {
                const int co = ct * 16 + cl;
                bf16x4 v = { (bf16_t)acc[a][ct][0], (bf16_t)acc[a][ct][1],
                             (bf16_t)acc[a][ct][2], (bf16_t)acc[a][ct][3] };
                *reinterpret_cast<bf16x4*>(&D[co * 128 + (ro0 ^ ((co & 7) << 3))]) = v;
            }
        }
    };

    for (int it = 0; it < 4; it++) {
        NSMM(sSn);
        WRT(sTT);
        __syncthreads();
        NSMM(sTT);
        __syncthreads();
        WRT(sTT);
        __syncthreads();
        NSMM(sTT);
        #pragma unroll
        for (int a = 0; a < 2; a++) {
            const int ro0 = w * 32 + a * 16 + kq * 4;
            #pragma unroll
            for (int ct = 0; ct < 8; ct++) {
                const int co = ct * 16 + cl;
                const int ix = co * 128 + (ro0 ^ ((co & 7) << 3));
                bf16x4 ph4 = *reinterpret_cast<const bf16x4*>(&sPh[ix]);
                bf16x4 pl4 = *reinterpret_cast<const bf16x4*>(&sPl[ix]);
                bf16x4 nh, nl;
                #pragma unroll
                for (int r = 0; r < 4; r++) {
                    const float pold = (float)ph4[r] + (float)pl4[r];
                    const float pn = 1.5f * pold - 0.5f * acc[a][ct][r];
                    nh[r] = (bf16_t)pn;
                    nl[r] = (bf16_t)(pn - (float)nh[r]);
                }
                *reinterpret_cast<bf16x4*>(&sPh[ix]) = nh;
                *reinterpret_cast<bf16x4*>(&sPl[ix]) = nl;
            }
        }
        __syncthreads();
    }

    const float scal = sqrtf(rTr);
    #pragma unroll
    for (int a = 0; a < 2; a++)
        #pragma unroll
        for (int ct = 0; ct < 8; ct++) acc[a][ct] = (f32x4){0.f, 0.f, 0.f, 0.f};
    #pragma unroll
    for (int kb = 0; kb < 4; kb++) {
        const int k0 = kb * 32 + kq * 8;
        bf16x8 ah[2], al[2];
        #pragma unroll
        for (int a = 0; a < 2; a++) {
            const int ra = w * 32 + a * 16 + cl;
            const float4 rv0 = *reinterpret_cast<const float4*>(&Rg[ra * 128 + k0]);
            const float4 rv1 = *reinterpret_cast<const float4*>(&Rg[ra * 128 + k0 + 4]);
            const float rv[8] = {rv0.x, rv0.y, rv0.z, rv0.w, rv1.x, rv1.y, rv1.z, rv1.w};
            bf16x8 h, l;
            #pragma unroll
            for (int j = 0; j < 8; j++) {
                h[j] = (bf16_t)rv[j];
                l[j] = (bf16_t)(rv[j] - (float)h[j]);
            }
            ah[a] = h; al[a] = l;
        }
        #pragma unroll
        for (int ct = 0; ct < 8; ct++) {
            const int rb = ct * 16 + cl;
            const int ib = rb * 128 + (k0 ^ ((rb & 7) << 3));
            const bf16x8 bh = *reinterpret_cast<const bf16x8*>(&sPh[ib]);
            const bf16x8 bl = *reinterpret_cast<const bf16x8*>(&sPl[ib]);
            #pragma unroll
            for (int a = 0; a < 2; a++) {
                acc[a][ct] = __builtin_amdgcn_mfma_f32_16x16x32_bf16(ah[a], bh, acc[a][ct], 0, 0, 0);
                acc[a][ct] = __builtin_amdgcn_mfma_f32_16x16x32_bf16(al[a], bh, acc[a][ct], 0, 0, 0);
                acc[a][ct] = __builtin_amdgcn_mfma_f32_16x16x32_bf16(ah[a], bl, acc[a][ct], 0, 0, 0);
            }
        }
    }
    #pragma unroll
    for (int a = 0; a < 2; a++) {
        float pb[4] = {0.f, 0.f, 0.f, 0.f};
        #pragma unroll
        for (int ct = 0; ct < 8; ct++) {
            const float mv = mean[ct * 16 + cl];
            #pragma unroll
            for (int r = 0; r < 4; r++) {
                const float wv = acc[a][ct][r] * scal;
                Wb[(w * 32 + a * 16 + kq * 4 + r) * 128 + ct * 16 + cl] = (bf16_t)wv;
                pb[r] += wv * mv;
            }
        }
        #pragma unroll
        for (int r = 0; r < 4; r++) {
            float v = pb[r];
            v += __shfl_xor(v, 1);
            v += __shfl_xor(v, 2);
            v += __shfl_xor(v, 4);
            v += __shfl_xor(v, 8);
            if (cl == 0) bias[w * 32 + a * 16 + kq * 4 + r] = v;
        }
    }
}

// ============ Kernel 4: out = X * W^T - bias (bf16 MFMA, split-X) ===========
// OPERAND-SWAPPED: mfma(W_frag, X_frag) -> D row = d, col = n. Each lane's 4
// acc values are 4 consecutive d's of one output row -> f32x4 NONTEMPORAL
// stores (32 scalar stores -> 8 dwordx4 nt). Bitwise-identical arithmetic.
__global__ __launch_bounds__(256) void k_out(const float* __restrict__ X,
        const bf16_t* __restrict__ Wb, const float* __restrict__ bias,
        float* __restrict__ out) {
    __shared__ bf16_t sW[128][136];
    __shared__ float sBias[128];
    const int t = threadIdx.x;
    const int w = t >> 6, lane = t & 63;
    const int cl = lane & 15, kq = lane >> 4;
    const int tile = NCHK - 1 - blockIdx.x;          // reverse order (L3 tail reuse)
    const size_t rowbase = (size_t)tile * 64 + (size_t)w * 16;
    const bool valid = rowbase < NROWS;    // wave-uniform (NROWS%16==0)

    // X loads first: longest latency, overlap W staging below.
    float4 B[8];
    {
        const float* xr = X + (rowbase + cl) * 128;
        #pragma unroll
        for (int kb = 0; kb < 4; kb++) {
            B[2*kb]   = valid ? *reinterpret_cast<const float4*>(xr + kb*32 + kq*8)
                              : float4{0.f,0.f,0.f,0.f};
            B[2*kb+1] = valid ? *reinterpret_cast<const float4*>(xr + kb*32 + kq*8 + 4)
                              : float4{0.f,0.f,0.f,0.f};
        }
    }
    #pragma unroll
    for (int i = 0; i < 8; i++) {          // W staging: 8 x 16B per thread
        const int idx = (t + (i << 8)) << 3;
        *reinterpret_cast<bf16x8*>(&sW[idx >> 7][idx & 127]) =
            *reinterpret_cast<const bf16x8*>(&Wb[idx]);
    }
    if (t < 128) sBias[t] = bias[t];
    __syncthreads();
    if (!valid) return;

    bf16x8 xh[4], xl[4];
    #pragma unroll
    for (int kb = 0; kb < 4; kb++) {
        const float4 v0 = B[2*kb], v1 = B[2*kb+1];
        const float xv[8] = {v0.x, v0.y, v0.z, v0.w, v1.x, v1.y, v1.z, v1.w};
        bf16x8 h, l;
        #pragma unroll
        for (int j = 0; j < 8; j++) {
            h[j] = (bf16_t)xv[j];
            l[j] = (bf16_t)(xv[j] - (float)h[j]);
        }
        xh[kb] = h; xl[kb] = l;
    }
    float* orow = out + (rowbase + cl) * 128;
    #pragma unroll
    for (int ct = 0; ct < 8; ct++) {
        f32x4 acc = (f32x4){0.f, 0.f, 0.f, 0.f};
        const int d = ct * 16 + cl;        // A-operand row (i = lane&15 = cl)
        #pragma unroll
        for (int kb = 0; kb < 4; kb++) {
            const bf16x8 wf = *reinterpret_cast<const bf16x8*>(&sW[d][kb*32 + kq*8]);
            acc = __builtin_amdgcn_mfma_f32_16x16x32_bf16(wf, xl[kb], acc, 0, 0, 0);
            acc = __builtin_amdgcn_mfma_f32_16x16x32_bf16(wf, xh[kb], acc, 0, 0, 0);
        }
        const f32x4 bv = *reinterpret_cast<const f32x4*>(&sBias[ct * 16 + kq * 4]);
        const f32x4 o = acc - bv;
        __builtin_nontemporal_store(o,
            reinterpret_cast<f32x4*>(&orow[ct * 16 + kq * 4]));
    }
}

extern "C" void kernel_launch(void* const* d_in, const int* in_sizes, int n_in,
                              void* d_out, int out_size, void* d_ws, size_t ws_size,
                              hipStream_t stream) {
    const float* X = (const float*)d_in[0];
    const float* R = (const float*)d_in[1];   // running_rot[0], row-major [d][c]
    float* out = (float*)d_out;
    char* ws = (char*)d_ws;
    float*  gramTot = (float*)(ws + GT_OFF);
    bf16_t* Wb      = (bf16_t*)(ws + WB_OFF);
    float*  mean    = (float*)(ws + MEAN_OFF);
    float*  bias    = (float*)(ws + BIAS_OFF);
    float*  csPart  = (float*)(ws + CS_OFF);

    int G = 512;
    size_t avail = (ws_size > GRAM_OFF) ? (ws_size - GRAM_OFF) : 0;
    if (avail < (size_t)G * 65536) {
        G = (int)(avail / 65536);
        if (G < 1) G = 1;
        if (G > 512) G = 512;
    }
    float* gramPart = (float*)(ws + GRAM_OFF);

    k_stats<<<dim3(G), dim3(256), 0, stream>>>(X, csPart, gramPart);
    k_gred<<<dim3(257), dim3(256), 0, stream>>>(gramPart, csPart, gramTot, mean, G);
    k_ns<<<dim3(1), dim3(256), 0, stream>>>(gramTot, mean, R, Wb, bias);
    k_out<<<dim3(NCHK), dim3(256), 0, stream>>>(X, Wb, bias, out);
}

// Round 11
// 199.610 us; speedup vs baseline: 1.1159x; 1.0537x over previous
//
#include <hip/hip_runtime.h>
#include <math.h>

#define NROWS  500000
#define NCHK   7813      // ceil(500000/64)
#define EPSV   1e-5f

typedef __bf16 bf16_t;
typedef __bf16 bf16x4 __attribute__((ext_vector_type(4)));
typedef __bf16 bf16x8 __attribute__((ext_vector_type(8)));
typedef float  f32x4  __attribute__((ext_vector_type(4)));

// ---- ws layout (byte offsets) ----
static const size_t GT_OFF   = 131072;   // gramTot 16384 f32 (64KB)
static const size_t WB_OFF   = 327680;   // W bf16 (32KB)
static const size_t MEAN_OFF = 360448;   // 128 f32
static const size_t BIAS_OFF = 360960;   // 128 f32
static const size_t CS_OFF   = 393216;   // colsum partials G*128 f32
static const size_t GRAM_OFF = 1048576;  // gram partials G*16384 f32

// ============ Kernel 1: column sums + Gram partials (bf16 MFMA) =============
// Main loop UNCHANGED from rounds 6-10 (verified). Epilogue: Gram is symmetric
// -> store acc[a][b] (4 consecutive ROWS, one col) at the TRANSPOSED position
// = one contiguous f32x4; nontemporal (write-once stream, keep X in L2/L3).
__global__ __launch_bounds__(256) void k_stats(const float* __restrict__ X,
        float* __restrict__ csPart, float* __restrict__ gramPart) {
    __shared__ bf16_t sxtT[2][8192];    // [buf][f-major 128x64 swizzled] 32KB
    __shared__ float  scs[256][4];
    const int t    = threadIdx.x;
    const int lane = t & 63;
    const int w    = t >> 6;     // wave 0..3
    const int oct  = t >> 5;     // sample octet 0..7
    const int fg4  = t & 31;     // feature quad 0..31
    const int cl   = lane & 15;
    const int kq   = lane >> 4;
    const int G    = gridDim.x;

    f32x4 acc[2][8];
    #pragma unroll
    for (int a = 0; a < 2; a++)
        #pragma unroll
        for (int b = 0; b < 8; b++)
            acc[a][b] = (f32x4){0.f, 0.f, 0.f, 0.f};
    float cs0 = 0.f, cs1 = 0.f, cs2 = 0.f, cs3 = 0.f;

    f32x4 R[8];

    auto KF = [](int f) { return (f ^ (f >> 3)) & 7; };

    auto GLOADC = [&](int ch) {
        const size_t row0 = (size_t)ch << 6;
        #pragma unroll
        for (int i = 0; i < 8; i++) {
            const size_t row = row0 + oct * 8 + i;
            R[i] = (row < NROWS)
                 ? *reinterpret_cast<const f32x4*>(X + row * 128 + fg4 * 4)
                 : (f32x4){0.f, 0.f, 0.f, 0.f};
        }
    };
    auto DSWRITEC = [&](int buf) {
        #pragma unroll
        for (int i = 0; i < 8; i++) {
            cs0 += R[i][0]; cs1 += R[i][1]; cs2 += R[i][2]; cs3 += R[i][3];
        }
        bf16_t* S = sxtT[buf];
        #pragma unroll
        for (int j = 0; j < 4; j++) {
            const int f = fg4 * 4 + j;
            const int g = oct ^ KF(f);
            bf16x8 v;
            #pragma unroll
            for (int i = 0; i < 8; i++) v[i] = (bf16_t)R[i][j];
            *reinterpret_cast<bf16x8*>(&S[f * 64 + g * 8]) = v;
        }
    };
    auto MFMAC = [&](int buf) {
        const bf16_t* S = sxtT[buf];
        #pragma unroll
        for (int kb = 0; kb < 2; kb++) {
            const int gq = kb * 4 + kq;            // sample-group index
            bf16x8 fa[2];
            #pragma unroll
            for (int a = 0; a < 2; a++) {
                const int f = (w * 2 + a) * 16 + cl;
                fa[a] = *reinterpret_cast<const bf16x8*>(&S[f * 64 + ((gq ^ KF(f)) << 3)]);
            }
            #pragma unroll
            for (int b = 0; b < 8; b++) {
                const int f = b * 16 + cl;
                const bf16x8 fb = *reinterpret_cast<const bf16x8*>(&S[f * 64 + ((gq ^ KF(f)) << 3)]);
                acc[0][b] = __builtin_amdgcn_mfma_f32_16x16x32_bf16(fa[0], fb, acc[0][b], 0, 0, 0);
                acc[1][b] = __builtin_amdgcn_mfma_f32_16x16x32_bf16(fa[1], fb, acc[1][b], 0, 0, 0);
            }
        }
    };

    int ch0 = blockIdx.x;
    GLOADC(ch0);
    DSWRITEC(0);
    __syncthreads();
    for (;;) {
        const int ch1 = ch0 + G;
        const bool v1 = ch1 < NCHK;
        if (v1) GLOADC(ch1);
        MFMAC(0);
        if (v1) DSWRITEC(1);
        __syncthreads();
        if (!v1) break;
        const int ch2 = ch1 + G;
        const bool v2 = ch2 < NCHK;
        if (v2) GLOADC(ch2);
        MFMAC(1);
        if (v2) DSWRITEC(0);
        __syncthreads();
        if (!v2) break;
        ch0 = ch2;
    }

    // Epilogue: transposed contiguous f32x4 nt stores (Gram^T == Gram).
    float* gp = gramPart + (size_t)blockIdx.x * 16384;
    #pragma unroll
    for (int a = 0; a < 2; a++)
        #pragma unroll
        for (int b = 0; b < 8; b++) {
            const int col  = b * 16 + cl;
            const int row0 = (w * 2 + a) * 16 + kq * 4;
            __builtin_nontemporal_store(acc[a][b],
                reinterpret_cast<f32x4*>(&gp[col * 128 + row0]));
        }
    scs[t][0] = cs0; scs[t][1] = cs1; scs[t][2] = cs2; scs[t][3] = cs3;
    __syncthreads();
    if (t < 128) {
        float s = 0.f;
        #pragma unroll
        for (int q = 0; q < 8; q++) s += scs[q * 32 + (t >> 2)][t & 3];
        csPart[(size_t)blockIdx.x * 128 + t] = s;
    }
}

// ============ Kernel 2: full coalesced reduction -> gramTot + mean ==========
// Round-8 structure (verified); gramPart reads are nontemporal (read-once).
__global__ __launch_bounds__(256) void k_gred(const float* __restrict__ gramPart,
        const float* __restrict__ csPart, float* __restrict__ gramTot,
        float* __restrict__ mean, int G) {
    const int t = threadIdx.x;
    const int b = blockIdx.x;
    if (b == 256) {                       // ---- mean ----
        if (t < 128) {
            float s = 0.f;
            int g = 0;
            for (; g + 8 <= G; g += 8) {
                float p[8];
                #pragma unroll
                for (int u = 0; u < 8; u++) p[u] = csPart[(size_t)(g + u) * 128 + t];
                s += ((p[0] + p[1]) + (p[2] + p[3])) + ((p[4] + p[5]) + (p[6] + p[7]));
            }
            for (; g < G; g++) s += csPart[(size_t)g * 128 + t];
            mean[t] = s * (1.0f / (float)NROWS);
        }
        return;
    }
    const int e  = b * 64 + (t & 63);
    const int sl = t >> 6;                // g-slice 0..3
    float s = 0.f;
    int g = sl;
    for (; g + 28 < G; g += 32) {         // 8 loads of stride-4 per iter
        float v[8];
        #pragma unroll
        for (int u = 0; u < 8; u++)
            v[u] = __builtin_nontemporal_load(&gramPart[(size_t)(g + 4 * u) * 16384 + e]);
        s += ((v[0] + v[1]) + (v[2] + v[3])) + ((v[4] + v[5]) + (v[6] + v[7]));
    }
    for (; g < G; g += 4)
        s += __builtin_nontemporal_load(&gramPart[(size_t)g * 16384 + e]);
    __shared__ float red[4][64];
    red[sl][t & 63] = s;
    __syncthreads();
    if (t < 64)
        gramTot[b * 64 + t] = (red[0][t] + red[1][t]) + (red[2][t] + red[3][t]);
}

// ============ Kernel 3: fused Sigma->Sn, Newton-Schulz x5, W, bias ==========
// UNCHANGED from round 9/10 (verified).
__global__ __launch_bounds__(256) void k_ns(const float* __restrict__ gramTot,
        const float* __restrict__ mean, const float* __restrict__ Rg,
        bf16_t* __restrict__ Wb, float* __restrict__ bias) {
    __shared__ bf16_t sPh[16384], sPl[16384], sSn[16384], sTT[16384];
    const int t = threadIdx.x;
    const int w = t >> 6, lane = t & 63;
    const int cl = lane & 15, kq = lane >> 4;

    float* rs = reinterpret_cast<float*>(sTT);
    float dv = 0.f;
    if (t < 128) {
        const float m = mean[t];
        dv = gramTot[t * 129] * (1.0f / (float)NROWS) - m * m + EPSV;
    }
    rs[t] = dv;
    __syncthreads();
    #pragma unroll
    for (int off = 128; off > 0; off >>= 1) {
        if (t < off) rs[t] += rs[t + off];
        __syncthreads();
    }
    const float rTr = 1.0f / rs[0];
    __syncthreads();
    for (int i = 0; i < 64; i++) {
        const int e = t + (i << 8);
        const int r = e >> 7, c = e & 127;
        float s = gramTot[e] * (1.0f / (float)NROWS) - mean[r] * mean[c];
        if (r == c) s += EPSV;
        const int ix = r * 128 + (c ^ ((r & 7) << 3));
        const float snv = s * rTr;
        sSn[ix] = (bf16_t)snv;
        const float p0 = ((r == c) ? 1.5f : 0.f) - 0.5f * snv;
        const bf16_t ph = (bf16_t)p0;
        sPh[ix] = ph;
        sPl[ix] = (bf16_t)(p0 - (float)ph);
    }
    __syncthreads();

    f32x4 acc[2][8];
    auto NSMM = [&](const bf16_t* __restrict__ Bm) {
        #pragma unroll
        for (int a = 0; a < 2; a++)
            #pragma unroll
            for (int ct = 0; ct < 8; ct++) acc[a][ct] = (f32x4){0.f, 0.f, 0.f, 0.f};
        #pragma unroll
        for (int kb = 0; kb < 4; kb++) {
            const int k0 = kb * 32 + kq * 8;
            bf16x8 ah[2], al[2];
            #pragma unroll
            for (int a = 0; a < 2; a++) {
                const int ra = w * 32 + a * 16 + cl;
                const int ia = ra * 128 + (k0 ^ ((ra & 7) << 3));
                ah[a] = *reinterpret_cast<const bf16x8*>(&sPh[ia]);
                al[a] = *reinterpret_cast<const bf16x8*>(&sPl[ia]);
            }
            #pragma unroll
            for (int ct = 0; ct < 8; ct++) {
                const int rb = ct * 16 + cl;
                const bf16x8 bb = *reinterpret_cast<const bf16x8*>(
                    &Bm[rb * 128 + (k0 ^ ((rb & 7) << 3))]);
                acc[0][ct] = __builtin_amdgcn_mfma_f32_16x16x32_bf16(ah[0], bb, acc[0][ct], 0, 0, 0);
                acc[0][ct] = __builtin_amdgcn_mfma_f32_16x16x32_bf16(al[0], bb, acc[0][ct], 0, 0, 0);
                acc[1][ct] = __builtin_amdgcn_mfma_f32_16x16x32_bf16(ah[1], bb, acc[1][ct], 0, 0, 0);
                acc[1][ct] = __builtin_amdgcn_mfma_f32_16x16x32_bf16(al[1], bb, acc[1][ct], 0, 0, 0);
            }
        }
    };
    auto WRT = [&](bf16_t* __restrict__ D) {
        #pragma unroll
        for (int a = 0; a < 2; a++) {
            const int ro0 = w * 32 + a * 16 + kq * 4;
            #pragma unroll
            for (int ct = 0; ct < 8; ct++) {
                const int co = ct * 16 + cl;
                bf16x4 v = { (bf16_t)acc[a][ct][0], (bf16_t)acc[a][ct][1],
                             (bf16_t)acc[a][ct][2], (bf16_t)acc[a][ct][3] };
                *reinterpret_cast<bf16x4*>(&D[co * 128 + (ro0 ^ ((co & 7) << 3))]) = v;
            }
        }
    };

    for (int it = 0; it < 4; it++) {
        NSMM(sSn);
        WRT(sTT);
        __syncthreads();
        NSMM(sTT);
        __syncthreads();
        WRT(sTT);
        __syncthreads();
        NSMM(sTT);
        #pragma unroll
        for (int a = 0; a < 2; a++) {
            const int ro0 = w * 32 + a * 16 + kq * 4;
            #pragma unroll
            for (int ct = 0; ct < 8; ct++) {
                const int co = ct * 16 + cl;
                const int ix = co * 128 + (ro0 ^ ((co & 7) << 3));
                bf16x4 ph4 = *reinterpret_cast<const bf16x4*>(&sPh[ix]);
                bf16x4 pl4 = *reinterpret_cast<const bf16x4*>(&sPl[ix]);
                bf16x4 nh, nl;
                #pragma unroll
                for (int r = 0; r < 4; r++) {
                    const float pold = (float)ph4[r] + (float)pl4[r];
                    const float pn = 1.5f * pold - 0.5f * acc[a][ct][r];
                    nh[r] = (bf16_t)pn;
                    nl[r] = (bf16_t)(pn - (float)nh[r]);
                }
                *reinterpret_cast<bf16x4*>(&sPh[ix]) = nh;
                *reinterpret_cast<bf16x4*>(&sPl[ix]) = nl;
            }
        }
        __syncthreads();
    }

    const float scal = sqrtf(rTr);
    #pragma unroll
    for (int a = 0; a < 2; a++)
        #pragma unroll
        for (int ct = 0; ct < 8; ct++) acc[a][ct] = (f32x4){0.f, 0.f, 0.f, 0.f};
    #pragma unroll
    for (int kb = 0; kb < 4; kb++) {
        const int k0 = kb * 32 + kq * 8;
        bf16x8 ah[2], al[2];
        #pragma unroll
        for (int a = 0; a < 2; a++) {
            const int ra = w * 32 + a * 16 + cl;
            const float4 rv0 = *reinterpret_cast<const float4*>(&Rg[ra * 128 + k0]);
            const float4 rv1 = *reinterpret_cast<const float4*>(&Rg[ra * 128 + k0 + 4]);
            const float rv[8] = {rv0.x, rv0.y, rv0.z, rv0.w, rv1.x, rv1.y, rv1.z, rv1.w};
            bf16x8 h, l;
            #pragma unroll
            for (int j = 0; j < 8; j++) {
                h[j] = (bf16_t)rv[j];
                l[j] = (bf16_t)(rv[j] - (float)h[j]);
            }
            ah[a] = h; al[a] = l;
        }
        #pragma unroll
        for (int ct = 0; ct < 8; ct++) {
            const int rb = ct * 16 + cl;
            const int ib = rb * 128 + (k0 ^ ((rb & 7) << 3));
            const bf16x8 bh = *reinterpret_cast<const bf16x8*>(&sPh[ib]);
            const bf16x8 bl = *reinterpret_cast<const bf16x8*>(&sPl[ib]);
            #pragma unroll
            for (int a = 0; a < 2; a++) {
                acc[a][ct] = __builtin_amdgcn_mfma_f32_16x16x32_bf16(ah[a], bh, acc[a][ct], 0, 0, 0);
                acc[a][ct] = __builtin_amdgcn_mfma_f32_16x16x32_bf16(al[a], bh, acc[a][ct], 0, 0, 0);
                acc[a][ct] = __builtin_amdgcn_mfma_f32_16x16x32_bf16(ah[a], bl, acc[a][ct], 0, 0, 0);
            }
        }
    }
    #pragma unroll
    for (int a = 0; a < 2; a++) {
        float pb[4] = {0.f, 0.f, 0.f, 0.f};
        #pragma unroll
        for (int ct = 0; ct < 8; ct++) {
            const float mv = mean[ct * 16 + cl];
            #pragma unroll
            for (int r = 0; r < 4; r++) {
                const float wv = acc[a][ct][r] * scal;
                Wb[(w * 32 + a * 16 + kq * 4 + r) * 128 + ct * 16 + cl] = (bf16_t)wv;
                pb[r] += wv * mv;
            }
        }
        #pragma unroll
        for (int r = 0; r < 4; r++) {
            float v = pb[r];
            v += __shfl_xor(v, 1);
            v += __shfl_xor(v, 2);
            v += __shfl_xor(v, 4);
            v += __shfl_xor(v, 8);
            if (cl == 0) bias[w * 32 + a * 16 + kq * 4 + r] = v;
        }
    }
}

// ============ Kernel 4: out = X * W^T - bias (bf16 MFMA, split-X) ===========
// Grid-stride 1024 blocks: W staged ONCE per block; X register double-buffer
// (prefetch tile t+G during compute of t); swapped-operand MFMA (row = d) and
// f32x4 nontemporal stores (round-10 verified arithmetic, unchanged bitwise).
__global__ __launch_bounds__(256, 4) void k_out(const float* __restrict__ X,
        const bf16_t* __restrict__ Wb, const float* __restrict__ bias,
        float* __restrict__ out) {
    __shared__ bf16_t sW[128][136];
    __shared__ float sBias[128];
    const int t = threadIdx.x;
    const int w = t >> 6, lane = t & 63;
    const int cl = lane & 15, kq = lane >> 4;
    const int G = gridDim.x;

    float4 A0[8], A1[8];

    auto GLOAD = [&](int tl, float4 (&B)[8]) {
        const size_t rowb = (size_t)tl * 64 + (size_t)w * 16;
        const bool v = rowb < NROWS;          // wave-uniform (NROWS%16==0)
        const float* xr = X + (rowb + cl) * 128;
        #pragma unroll
        for (int kb = 0; kb < 4; kb++) {
            B[2*kb]   = v ? *reinterpret_cast<const float4*>(xr + kb*32 + kq*8)
                          : float4{0.f,0.f,0.f,0.f};
            B[2*kb+1] = v ? *reinterpret_cast<const float4*>(xr + kb*32 + kq*8 + 4)
                          : float4{0.f,0.f,0.f,0.f};
        }
    };
    auto COMPSTORE = [&](int tl, const float4 (&B)[8]) {
        const size_t rowbase = (size_t)tl * 64 + (size_t)w * 16;
        if (rowbase >= NROWS) return;         // no barriers in loop: safe
        bf16x8 xh[4], xl[4];
        #pragma unroll
        for (int kb = 0; kb < 4; kb++) {
            const float4 v0 = B[2*kb], v1 = B[2*kb+1];
            const float xv[8] = {v0.x, v0.y, v0.z, v0.w, v1.x, v1.y, v1.z, v1.w};
            bf16x8 h, l;
            #pragma unroll
            for (int j = 0; j < 8; j++) {
                h[j] = (bf16_t)xv[j];
                l[j] = (bf16_t)(xv[j] - (float)h[j]);
            }
            xh[kb] = h; xl[kb] = l;
        }
        float* orow = out + (rowbase + cl) * 128;
        #pragma unroll
        for (int ct = 0; ct < 8; ct++) {
            f32x4 acc = (f32x4){0.f, 0.f, 0.f, 0.f};
            const int d = ct * 16 + cl;
            #pragma unroll
            for (int kb = 0; kb < 4; kb++) {
                const bf16x8 wf = *reinterpret_cast<const bf16x8*>(&sW[d][kb*32 + kq*8]);
                acc = __builtin_amdgcn_mfma_f32_16x16x32_bf16(wf, xl[kb], acc, 0, 0, 0);
                acc = __builtin_amdgcn_mfma_f32_16x16x32_bf16(wf, xh[kb], acc, 0, 0, 0);
            }
            const f32x4 bv = *reinterpret_cast<const f32x4*>(&sBias[ct * 16 + kq * 4]);
            const f32x4 o = acc - bv;
            __builtin_nontemporal_store(o,
                reinterpret_cast<f32x4*>(&orow[ct * 16 + kq * 4]));
        }
    };

    int t0 = blockIdx.x;                      // G=1024 < NCHK: all blocks work
    GLOAD(t0, A0);                            // issue X before W staging
    #pragma unroll
    for (int i = 0; i < 8; i++) {             // W staging: 8 x 16B per thread
        const int idx = (t + (i << 8)) << 3;
        *reinterpret_cast<bf16x8*>(&sW[idx >> 7][idx & 127]) =
            *reinterpret_cast<const bf16x8*>(&Wb[idx]);
    }
    if (t < 128) sBias[t] = bias[t];
    __syncthreads();
    for (;;) {
        const int t1 = t0 + G;
        if (t1 < NCHK) GLOAD(t1, A1);         // prefetch next while computing
        COMPSTORE(t0, A0);
        if (t1 >= NCHK) break;
        const int t2 = t1 + G;
        if (t2 < NCHK) GLOAD(t2, A0);
        COMPSTORE(t1, A1);
        if (t2 >= NCHK) break;
        t0 = t2;
    }
}

extern "C" void kernel_launch(void* const* d_in, const int* in_sizes, int n_in,
                              void* d_out, int out_size, void* d_ws, size_t ws_size,
                              hipStream_t stream) {
    const float* X = (const float*)d_in[0];
    const float* R = (const float*)d_in[1];   // running_rot[0], row-major [d][c]
    float* out = (float*)d_out;
    char* ws = (char*)d_ws;
    float*  gramTot = (float*)(ws + GT_OFF);
    bf16_t* Wb      = (bf16_t*)(ws + WB_OFF);
    float*  mean    = (float*)(ws + MEAN_OFF);
    float*  bias    = (float*)(ws + BIAS_OFF);
    float*  csPart  = (float*)(ws + CS_OFF);

    int G = 512;
    size_t avail = (ws_size > GRAM_OFF) ? (ws_size - GRAM_OFF) : 0;
    if (avail < (size_t)G * 65536) {
        G = (int)(avail / 65536);
        if (G < 1) G = 1;
        if (G > 512) G = 512;
    }
    float* gramPart = (float*)(ws + GRAM_OFF);

    k_stats<<<dim3(G), dim3(256), 0, stream>>>(X, csPart, gramPart);
    k_gred<<<dim3(257), dim3(256), 0, stream>>>(gramPart, csPart, gramTot, mean, G);
    k_ns<<<dim3(1), dim3(256), 0, stream>>>(gramTot, mean, R, Wb, bias);
    k_out<<<dim3(1024), dim3(256), 0, stream>>>(X, Wb, bias, out);
}